// Round 22
// baseline (59.819 us; speedup 1.0000x reference)
//
#include <hip/hip_runtime.h>
#include <hip/hip_bf16.h>
#include <math.h>

// Problem constants
#define BB 2
#define NN 2048
#define DD 512
#define HH 8
#define VD 64

typedef _Float16 half8 __attribute__((ext_vector_type(8)));
typedef _Float16 half4 __attribute__((ext_vector_type(4)));
typedef __fp16 fp16x2 __attribute__((ext_vector_type(2)));
typedef float f32x4 __attribute__((ext_vector_type(4)));

#define GLDS16(gp, lp) __builtin_amdgcn_global_load_lds( \
    (const __attribute__((address_space(1))) void*)(gp), \
    (__attribute__((address_space(3))) void*)(lp), 16, 0, 0)

__device__ __forceinline__ float fexp2(float x) {
#if __has_builtin(__builtin_amdgcn_exp2f)
    return __builtin_amdgcn_exp2f(x);
#else
    return exp2f(x);
#endif
}

__device__ __forceinline__ void stage8(const _Float16* gsrc, size_t ldg, int r0,
                                       _Float16* lbase, int lane) {
    int r8 = lane >> 3;
    int ce = ((lane & 7) ^ r8) << 3;
    const _Float16* g = gsrc + (size_t)(r0 + r8) * ldg + ce;
    GLDS16(g, lbase);
}

// 128B-row tile, swizzle key row&7
__device__ __forceinline__ half8 frag_ld(const _Float16* tile, int row, int cb) {
    int off = row * 128 + (cb ^ ((row & 7) << 4));
    return *(const half8*)((const char*)tile + off);
}

__device__ __forceinline__ float gelu_exact(float v) {
    return 0.5f * v * (1.f + erff(v * 0.70710678118654752f));
}

#define SM_BYTES 66560

// ---------------------------------------------------------------------------
// Kernel 1: X f32->f16 cast (512 blocks) + weight transpose (blocks 0..191).
// ---------------------------------------------------------------------------
__global__ __launch_bounds__(256) void k_prep(
    const float* __restrict__ x,
    const float* __restrict__ qw, const float* __restrict__ kw,
    const float* __restrict__ vw,
    _Float16* __restrict__ wt, _Float16* __restrict__ xh)
{
    __shared__ __align__(16) float ls[64][65];
    const int bid = blockIdx.x, t = threadIdx.x;
#pragma unroll
    for (int j = 0; j < 2; ++j) {
        size_t idx = (((size_t)bid * 2 + j) * 256 + t) * 8;
        float4 a = *(const float4*)(x + idx);
        float4 b = *(const float4*)(x + idx + 4);
        half8 hv;
        hv[0] = (_Float16)a.x; hv[1] = (_Float16)a.y;
        hv[2] = (_Float16)a.z; hv[3] = (_Float16)a.w;
        hv[4] = (_Float16)b.x; hv[5] = (_Float16)b.y;
        hv[6] = (_Float16)b.z; hv[7] = (_Float16)b.w;
        *(half8*)(xh + idx) = hv;
    }
    if (bid < 192) {
        const int kc = bid & 7, h = (bid >> 3) & 7, ty = bid >> 6;
        const float* src = (ty == 0) ? qw : (ty == 1) ? kw : vw;
#pragma unroll
        for (int j = 0; j < 4; ++j) {
            int idx = t + 256 * j;
            int k = idx >> 4, o4 = idx & 15;
            float4 v = *(const float4*)(src + ((size_t)(h * DD + kc * 64 + k) * VD + o4 * 4));
            ls[k][o4 * 4 + 0] = v.x; ls[k][o4 * 4 + 1] = v.y;
            ls[k][o4 * 4 + 2] = v.z; ls[k][o4 * 4 + 3] = v.w;
        }
        __syncthreads();
#pragma unroll
        for (int j = 0; j < 4; ++j) {
            int idx = t + 256 * j;
            int o = idx >> 4, k4 = idx & 15;
            half4 hv;
#pragma unroll
            for (int i = 0; i < 4; ++i) hv[i] = (_Float16)ls[k4 * 4 + i][o];
            *(half4*)(wt + ((size_t)(ty * HH + h) * VD + o) * DD + kc * 64 + k4 * 4) = hv;
        }
    }
}

// ---------------------------------------------------------------------------
// Kernel 2: QKV projection (r21 verbatim): 64-row m-tiles, grid 512, counted
// vmcnt double-buffer, coalesced LDS-transpose epilogue, psi-permuted V.
// ---------------------------------------------------------------------------
__global__ __launch_bounds__(256) void k_proj(
    const _Float16* __restrict__ xh,
    const _Float16* __restrict__ wt,
    _Float16* __restrict__ qsp,
    _Float16* __restrict__ kbp,
    _Float16* __restrict__ vtp)
{
    __shared__ __align__(16) _Float16 xls[2][4096];
    __shared__ __align__(16) _Float16 wls[2][12288];
    const int bid = blockIdx.x, t = threadIdx.x;
    const int wave = t >> 6, lane = t & 63;
    const int lq = lane & 15, g = lane >> 4;
    const int h = bid & 7;
    const int m0 = (bid >> 3) * 64;
    const int rbase = 32 * (wave >> 1);
    const int cbase = 96 * (wave & 1);

    f32x4 acc[2][6];
#pragma unroll
    for (int a = 0; a < 2; ++a)
#pragma unroll
        for (int c = 0; c < 6; ++c) acc[a][c] = (f32x4){0.f, 0.f, 0.f, 0.f};

    auto stage = [&](int buf, int ks) {
#pragma unroll
        for (int j = 0; j < 2; ++j) {
            int i = wave * 2 + j;
            stage8(xh + (size_t)m0 * DD + ks * 64, DD, i * 8, &xls[buf][i * 512], lane);
        }
#pragma unroll
        for (int j = 0; j < 6; ++j) {
            int i = wave * 6 + j;
            int ty = i >> 3;
            int ol = (i & 7) * 8;
            stage8(wt + ((size_t)(ty * HH + h) * VD + ol) * DD + ks * 64, DD, 0,
                   &wls[buf][i * 512], lane);
        }
    };

    stage(0, 0);
    stage(1, 1);
    for (int ks = 0; ks < 8; ++ks) {
        const int buf = ks & 1;
        if (ks < 7) asm volatile("s_waitcnt vmcnt(8)" ::: "memory");
        else        asm volatile("s_waitcnt vmcnt(0)" ::: "memory");
        __builtin_amdgcn_s_barrier();
        half8 af[2][2];
        half8 bf[6][2];
#pragma unroll
        for (int amt = 0; amt < 2; ++amt) {
            af[amt][0] = frag_ld(xls[buf], rbase + amt * 16 + lq, 16 * g);
            af[amt][1] = frag_ld(xls[buf], rbase + amt * 16 + lq, 64 + 16 * g);
        }
#pragma unroll
        for (int ct = 0; ct < 6; ++ct) {
            int wr = cbase + ct * 16 + lq;
            bf[ct][0] = frag_ld(wls[buf], wr, 16 * g);
            bf[ct][1] = frag_ld(wls[buf], wr, 64 + 16 * g);
        }
        asm volatile("s_waitcnt lgkmcnt(0)" ::: "memory");
        __builtin_amdgcn_sched_barrier(0);
        __builtin_amdgcn_s_barrier();
        if (ks + 2 < 8) stage(buf, ks + 2);
        __builtin_amdgcn_s_setprio(1);
#pragma unroll
        for (int ct = 0; ct < 6; ++ct) {
#pragma unroll
            for (int amt = 0; amt < 2; ++amt) {
                acc[amt][ct] = __builtin_amdgcn_mfma_f32_16x16x32_f16(af[amt][0], bf[ct][0], acc[amt][ct], 0, 0, 0);
                acc[amt][ct] = __builtin_amdgcn_mfma_f32_16x16x32_f16(af[amt][1], bf[ct][1], acc[amt][ct], 0, 0, 0);
            }
        }
        __builtin_amdgcn_s_setprio(0);
    }

    // ---- coalesced epilogue via LDS transpose (reuse wls as scratch) ----
    const int b0 = m0 >> 11;
    const int nb0 = m0 & (NN - 1);
    const size_t bh = (size_t)(b0 * HH + h);
    _Float16* ldsA = &wls[0][0];
    _Float16* ldsV = &wls[0][0];
    const int rn = t >> 2;
    const int rc = t & 3;

    // Pass A: Q
    __syncthreads();
    if ((wave & 1) == 0) {
#pragma unroll
        for (int ct = 0; ct < 4; ++ct) {
            int o = ct * 16 + lq;
#pragma unroll
            for (int amt = 0; amt < 2; ++amt)
#pragma unroll
                for (int i = 0; i < 4; ++i) {
                    int n = rbase + amt * 16 + 4 * g + i;
                    ldsA[n * 72 + o] = (_Float16)(acc[amt][ct][i] * 0.18033688011112042f);
                }
        }
    }
    __syncthreads();
    {
        half8 v0 = *(const half8*)&ldsA[rn * 72 + rc * 16];
        half8 v1 = *(const half8*)&ldsA[rn * 72 + rc * 16 + 8];
        _Float16* qp = qsp + (bh * NN + nb0 + rn) * VD + rc * 16;
        *(half8*)qp = v0;
        *(half8*)(qp + 8) = v1;
    }

    // Pass B: K
    __syncthreads();
    if ((wave & 1) == 0) {
#pragma unroll
        for (int ct = 4; ct < 6; ++ct) {
            int o = (ct - 4) * 16 + lq;
#pragma unroll
            for (int amt = 0; amt < 2; ++amt)
#pragma unroll
                for (int i = 0; i < 4; ++i) {
                    int n = rbase + amt * 16 + 4 * g + i;
                    ldsA[n * 72 + o] = (_Float16)acc[amt][ct][i];
                }
        }
    } else {
#pragma unroll
        for (int ct = 0; ct < 2; ++ct) {
            int o = 32 + ct * 16 + lq;
#pragma unroll
            for (int amt = 0; amt < 2; ++amt)
#pragma unroll
                for (int i = 0; i < 4; ++i) {
                    int n = rbase + amt * 16 + 4 * g + i;
                    ldsA[n * 72 + o] = (_Float16)acc[amt][ct][i];
                }
        }
    }
    __syncthreads();
    {
        half8 v0 = *(const half8*)&ldsA[rn * 72 + rc * 16];
        half8 v1 = *(const half8*)&ldsA[rn * 72 + rc * 16 + 8];
        _Float16* kp = kbp + (bh * NN + nb0 + rn) * VD + rc * 16;
        *(half8*)kp = v0;
        *(half8*)(kp + 8) = v1;
    }

    // Pass C: V (psi folded into reads)
    __syncthreads();
    if (wave & 1) {
#pragma unroll
        for (int ct = 2; ct < 6; ++ct) {
            int o = (ct - 2) * 16 + lq;
#pragma unroll
            for (int amt = 0; amt < 2; ++amt) {
                int n0 = rbase + amt * 16 + 4 * g;
                half4 hv;
#pragma unroll
                for (int i = 0; i < 4; ++i) hv[i] = (_Float16)acc[amt][ct][i];
                *(half4*)&ldsV[o * 88 + n0] = hv;
            }
        }
    }
    __syncthreads();
    {
#pragma unroll
        for (int blk = 0; blk < 2; ++blk) {
            half4 lo = *(const half4*)&ldsV[rn * 88 + 32 * blk + 4 * rc];
            half4 hi = *(const half4*)&ldsV[rn * 88 + 32 * blk + 16 + 4 * rc];
            half8 pk;
            pk[0] = lo[0]; pk[1] = lo[1]; pk[2] = lo[2]; pk[3] = lo[3];
            pk[4] = hi[0]; pk[5] = hi[1]; pk[6] = hi[2]; pk[7] = hi[3];
            *(half8*)(vtp + (bh * VD + rn) * NN + nb0 + 32 * blk + 8 * rc) = pk;
        }
    }
}

// ---------------------------------------------------------------------------
// Kernel 3: flash attention v10 -- ZERO LDS in the k-loop. Every lane's K/V
// MFMA fragment is a contiguous 16B global region (psi-permuted V storage +
// swapped-QK layout), so fragments load DIRECTLY global->VGPR, software-
// pipelined one 128-kv tile ahead (A/B register sets). No barriers, no
// GLDS16, no staging. lsum via ones-MFMA, per-qg QK/softmax pipeline,
// no-max softmax. Epilogue (cross-wave LDS reduce + GELU) unchanged.
// ---------------------------------------------------------------------------
__global__ __launch_bounds__(256, 2) void k_attn(
    const _Float16* __restrict__ qs,
    const _Float16* __restrict__ kb,
    const _Float16* __restrict__ vt,
    float* __restrict__ out)
{
    constexpr int NITER = NN / 128;    // 16
    __shared__ __align__(16) char SM[SM_BYTES];
    const int bid = blockIdx.x, t = threadIdx.x;
    const int wave = t >> 6, lane = t & 63;
    const int lq = lane & 15, g = lane >> 4;
    const int xcd = bid & 7;
    const int bh = xcd * 2 + ((bid >> 3) & 1);
    const int qt = bid >> 4;
    const int qbase = qt * 64;

    half8 qf[4][2];
#pragma unroll
    for (int qg = 0; qg < 4; ++qg)
#pragma unroll
        for (int ds = 0; ds < 2; ++ds)
            qf[qg][ds] = *(const half8*)(qs + ((size_t)bh * NN + qbase + 16 * qg + lq) * VD + 32 * ds + 8 * g);

    // per-lane direct fragment base pointers (derived from the staged-LDS
    // algebra; element-identical to v9's frag_ld/frag_ldv results)
    const _Float16* kP = kb + ((size_t)bh * NN + 32 * wave + lq) * VD + 8 * g;
    const _Float16* vP = vt + ((size_t)bh * VD + lq) * NN + 32 * wave + 8 * g;

    f32x4 oacc[4][4];
    f32x4 oacc_l[4];
#pragma unroll
    for (int qg = 0; qg < 4; ++qg) {
#pragma unroll
        for (int dt = 0; dt < 4; ++dt) oacc[qg][dt] = (f32x4){0.f, 0.f, 0.f, 0.f};
        oacc_l[qg] = (f32x4){0.f, 0.f, 0.f, 0.f};
    }
    half8 vones;
#pragma unroll
    for (int i = 0; i < 8; ++i) vones[i] = (_Float16)1.0f;

    union PU { fp16x2 h2[4]; half8 h8; };

#define LOADK(DST, J)                                                            \
    _Pragma("unroll") for (int mt = 0; mt < 2; ++mt)                             \
        _Pragma("unroll") for (int ds = 0; ds < 2; ++ds)                         \
            DST[mt][ds] = *(const half8*)(kP + ((size_t)(J) * 128 + mt * 16) * VD + ds * 32);

#define LOADV(DST, J)                                                            \
    _Pragma("unroll") for (int dt = 0; dt < 4; ++dt)                             \
        DST[dt] = *(const half8*)(vP + (size_t)dt * 16 * NN + (J) * 128);

#define AT_COMP(KF, VF)                                                          \
    {                                                                            \
        f32x4 sc[2][2];                                                          \
        __builtin_amdgcn_s_setprio(1);                                           \
        _Pragma("unroll") for (int mt = 0; mt < 2; ++mt) {                       \
            sc[0][mt] = (f32x4){0.f, 0.f, 0.f, 0.f};                             \
            sc[0][mt] = __builtin_amdgcn_mfma_f32_16x16x32_f16(KF[mt][0], qf[0][0], sc[0][mt], 0, 0, 0); \
            sc[0][mt] = __builtin_amdgcn_mfma_f32_16x16x32_f16(KF[mt][1], qf[0][1], sc[0][mt], 0, 0, 0); \
        }                                                                        \
        _Pragma("unroll") for (int qg = 0; qg < 4; ++qg) {                       \
            const int cur = qg & 1;                                              \
            if (qg < 3) {                                                        \
                _Pragma("unroll") for (int mt = 0; mt < 2; ++mt) {               \
                    sc[cur ^ 1][mt] = (f32x4){0.f, 0.f, 0.f, 0.f};               \
                    sc[cur ^ 1][mt] = __builtin_amdgcn_mfma_f32_16x16x32_f16(KF[mt][0], qf[qg + 1][0], sc[cur ^ 1][mt], 0, 0, 0); \
                    sc[cur ^ 1][mt] = __builtin_amdgcn_mfma_f32_16x16x32_f16(KF[mt][1], qf[qg + 1][1], sc[cur ^ 1][mt], 0, 0, 0); \
                }                                                                \
            }                                                                    \
            PU pu;                                                               \
            {                                                                    \
                float p00 = fexp2(sc[cur][0][0]);                                \
                float p01 = fexp2(sc[cur][0][1]);                                \
                float p02 = fexp2(sc[cur][0][2]);                                \
                float p03 = fexp2(sc[cur][0][3]);                                \
                float p10 = fexp2(sc[cur][1][0]);                                \
                float p11 = fexp2(sc[cur][1][1]);                                \
                float p12 = fexp2(sc[cur][1][2]);                                \
                float p13 = fexp2(sc[cur][1][3]);                                \
                pu.h2[0] = __builtin_amdgcn_cvt_pkrtz(p00, p01);                 \
                pu.h2[1] = __builtin_amdgcn_cvt_pkrtz(p02, p03);                 \
                pu.h2[2] = __builtin_amdgcn_cvt_pkrtz(p10, p11);                 \
                pu.h2[3] = __builtin_amdgcn_cvt_pkrtz(p12, p13);                 \
            }                                                                    \
            _Pragma("unroll") for (int dt = 0; dt < 4; ++dt)                     \
                oacc[qg][dt] = __builtin_amdgcn_mfma_f32_16x16x32_f16(VF[dt], pu.h8, oacc[qg][dt], 0, 0, 0); \
            oacc_l[qg] = __builtin_amdgcn_mfma_f32_16x16x32_f16(vones, pu.h8, oacc_l[qg], 0, 0, 0); \
        }                                                                        \
        __builtin_amdgcn_s_setprio(0);                                           \
    }

    half8 kfA[2][2], vfA[4], kfB[2][2], vfB[4];
    LOADK(kfA, 0); LOADV(vfA, 0);
    LOADK(kfB, 1); LOADV(vfB, 1);
#pragma unroll
    for (int j = 0; j < NITER; j += 2) {
        AT_COMP(kfA, vfA);
        if (j + 2 < NITER) { LOADK(kfA, j + 2); LOADV(vfA, j + 2); }
        AT_COMP(kfB, vfB);
        if (j + 3 < NITER) { LOADK(kfB, j + 3); LOADV(vfB, j + 3); }
    }
#undef AT_COMP
#undef LOADV
#undef LOADK

    // ---- epilogue: cross-wave reduce (O, l) via LDS, normalize+GELU+store ----
    float* lsm  = (float*)(SM + 65536);
    float* sred = (float*)SM;
    __syncthreads();
    if (g == 0) {
#pragma unroll
        for (int qg = 0; qg < 4; ++qg) lsm[wave * 64 + 16 * qg + lq] = oacc_l[qg][0];
    }
#pragma unroll
    for (int qg = 0; qg < 4; ++qg)
#pragma unroll
        for (int dt = 0; dt < 4; ++dt)
            *(f32x4*)(sred + (size_t)wave * 4096 + (16 * qg + lq) * 64 + 16 * dt + 4 * g) = oacc[qg][dt];
    __syncthreads();
    const int b2 = bh >> 3, h = bh & 7;
    const int q = t >> 2, cg2 = t & 3;
    float lt = (lsm[q] + lsm[64 + q]) + (lsm[128 + q] + lsm[192 + q]);
    float inv = 1.f / lt;
    float* op = out + ((size_t)b2 * NN + qbase + q) * (HH * VD) + h * VD + 16 * cg2;
#pragma unroll
    for (int c2 = 0; c2 < 4; ++c2) {
        int off = q * 64 + 16 * cg2 + 4 * c2;
        f32x4 o = *(const f32x4*)(sred + off);
        o += *(const f32x4*)(sred + 4096 + off);
        o += *(const f32x4*)(sred + 8192 + off);
        o += *(const f32x4*)(sred + 12288 + off);
        float4 r;
        r.x = gelu_exact(o[0] * inv);
        r.y = gelu_exact(o[1] * inv);
        r.z = gelu_exact(o[2] * inv);
        r.w = gelu_exact(o[3] * inv);
        *(float4*)(op + 4 * c2) = r;
    }
}

// ---------------------------------------------------------------------------
extern "C" void kernel_launch(void* const* d_in, const int* in_sizes, int n_in,
                              void* d_out, int out_size, void* d_ws, size_t ws_size,
                              hipStream_t stream)
{
    const float* x  = (const float*)d_in[0];
    const float* qw = (const float*)d_in[1];
    const float* kw = (const float*)d_in[2];
    const float* vw = (const float*)d_in[3];
    float* out = (float*)d_out;

    _Float16* wt  = (_Float16*)d_ws;            // [3][H][VD][D]
    _Float16* xhp = wt  + 786432;               // [B*N][D]
    _Float16* qsp = xhp + 2097152;
    _Float16* kbp = qsp + 2097152;
    _Float16* vtp = kbp + 2097152;

    hipLaunchKernelGGL(k_prep, dim3(512), dim3(256), 0, stream,
                       x, qw, kw, vw, wt, xhp);
    hipLaunchKernelGGL(k_proj, dim3(512), dim3(256), 0, stream,
                       xhp, wt, qsp, kbp, vtp);
    hipLaunchKernelGGL(k_attn, dim3(512), dim3(256), 0, stream,
                       qsp, kbp, vtp, out);
}

// Round 23
// 47.063 us; speedup vs baseline: 1.2710x; 1.2710x over previous
//
#include <hip/hip_runtime.h>
#include <hip/hip_bf16.h>
#include <math.h>

// Problem constants
#define BB 2
#define NN 2048
#define DD 512
#define HH 8
#define VD 64

typedef _Float16 half8 __attribute__((ext_vector_type(8)));
typedef _Float16 half4 __attribute__((ext_vector_type(4)));
typedef __fp16 fp16x2 __attribute__((ext_vector_type(2)));
typedef float f32x4 __attribute__((ext_vector_type(4)));

#define GLDS16(gp, lp) __builtin_amdgcn_global_load_lds( \
    (const __attribute__((address_space(1))) void*)(gp), \
    (__attribute__((address_space(3))) void*)(lp), 16, 0, 0)

__device__ __forceinline__ float fexp2(float x) {
#if __has_builtin(__builtin_amdgcn_exp2f)
    return __builtin_amdgcn_exp2f(x);
#else
    return exp2f(x);
#endif
}

__device__ __forceinline__ void stage8(const _Float16* gsrc, size_t ldg, int r0,
                                       _Float16* lbase, int lane) {
    int r8 = lane >> 3;
    int ce = ((lane & 7) ^ r8) << 3;
    const _Float16* g = gsrc + (size_t)(r0 + r8) * ldg + ce;
    GLDS16(g, lbase);
}

// 128B-row tile, swizzle key row&7
__device__ __forceinline__ half8 frag_ld(const _Float16* tile, int row, int cb) {
    int off = row * 128 + (cb ^ ((row & 7) << 4));
    return *(const half8*)((const char*)tile + off);
}

__device__ __forceinline__ float gelu_exact(float v) {
    return 0.5f * v * (1.f + erff(v * 0.70710678118654752f));
}

#define SM_BYTES 70656   // 64KB staging; epilogue: sred 4*64*68*4=69632 + lsm 1024

// ---------------------------------------------------------------------------
// Kernel 1: X f32->f16 cast (512 blocks) + weight transpose (blocks 0..191).
// ---------------------------------------------------------------------------
__global__ __launch_bounds__(256) void k_prep(
    const float* __restrict__ x,
    const float* __restrict__ qw, const float* __restrict__ kw,
    const float* __restrict__ vw,
    _Float16* __restrict__ wt, _Float16* __restrict__ xh)
{
    __shared__ __align__(16) float ls[64][65];
    const int bid = blockIdx.x, t = threadIdx.x;
#pragma unroll
    for (int j = 0; j < 2; ++j) {
        size_t idx = (((size_t)bid * 2 + j) * 256 + t) * 8;
        float4 a = *(const float4*)(x + idx);
        float4 b = *(const float4*)(x + idx + 4);
        half8 hv;
        hv[0] = (_Float16)a.x; hv[1] = (_Float16)a.y;
        hv[2] = (_Float16)a.z; hv[3] = (_Float16)a.w;
        hv[4] = (_Float16)b.x; hv[5] = (_Float16)b.y;
        hv[6] = (_Float16)b.z; hv[7] = (_Float16)b.w;
        *(half8*)(xh + idx) = hv;
    }
    if (bid < 192) {
        const int kc = bid & 7, h = (bid >> 3) & 7, ty = bid >> 6;
        const float* src = (ty == 0) ? qw : (ty == 1) ? kw : vw;
#pragma unroll
        for (int j = 0; j < 4; ++j) {
            int idx = t + 256 * j;
            int k = idx >> 4, o4 = idx & 15;
            float4 v = *(const float4*)(src + ((size_t)(h * DD + kc * 64 + k) * VD + o4 * 4));
            ls[k][o4 * 4 + 0] = v.x; ls[k][o4 * 4 + 1] = v.y;
            ls[k][o4 * 4 + 2] = v.z; ls[k][o4 * 4 + 3] = v.w;
        }
        __syncthreads();
#pragma unroll
        for (int j = 0; j < 4; ++j) {
            int idx = t + 256 * j;
            int o = idx >> 4, k4 = idx & 15;
            half4 hv;
#pragma unroll
            for (int i = 0; i < 4; ++i) hv[i] = (_Float16)ls[k4 * 4 + i][o];
            *(half4*)(wt + ((size_t)(ty * HH + h) * VD + o) * DD + kc * 64 + k4 * 4) = hv;
        }
    }
}

// ---------------------------------------------------------------------------
// Kernel 2: QKV projection (r21 verbatim): 64-row m-tiles, grid 512, counted
// vmcnt double-buffer, coalesced LDS-transpose epilogue, psi-permuted V.
// ---------------------------------------------------------------------------
__global__ __launch_bounds__(256) void k_proj(
    const _Float16* __restrict__ xh,
    const _Float16* __restrict__ wt,
    _Float16* __restrict__ qsp,
    _Float16* __restrict__ kbp,
    _Float16* __restrict__ vtp)
{
    __shared__ __align__(16) _Float16 xls[2][4096];
    __shared__ __align__(16) _Float16 wls[2][12288];
    const int bid = blockIdx.x, t = threadIdx.x;
    const int wave = t >> 6, lane = t & 63;
    const int lq = lane & 15, g = lane >> 4;
    const int h = bid & 7;
    const int m0 = (bid >> 3) * 64;
    const int rbase = 32 * (wave >> 1);
    const int cbase = 96 * (wave & 1);

    f32x4 acc[2][6];
#pragma unroll
    for (int a = 0; a < 2; ++a)
#pragma unroll
        for (int c = 0; c < 6; ++c) acc[a][c] = (f32x4){0.f, 0.f, 0.f, 0.f};

    auto stage = [&](int buf, int ks) {
#pragma unroll
        for (int j = 0; j < 2; ++j) {
            int i = wave * 2 + j;
            stage8(xh + (size_t)m0 * DD + ks * 64, DD, i * 8, &xls[buf][i * 512], lane);
        }
#pragma unroll
        for (int j = 0; j < 6; ++j) {
            int i = wave * 6 + j;
            int ty = i >> 3;
            int ol = (i & 7) * 8;
            stage8(wt + ((size_t)(ty * HH + h) * VD + ol) * DD + ks * 64, DD, 0,
                   &wls[buf][i * 512], lane);
        }
    };

    stage(0, 0);
    stage(1, 1);
    for (int ks = 0; ks < 8; ++ks) {
        const int buf = ks & 1;
        if (ks < 7) asm volatile("s_waitcnt vmcnt(8)" ::: "memory");
        else        asm volatile("s_waitcnt vmcnt(0)" ::: "memory");
        __builtin_amdgcn_s_barrier();
        half8 af[2][2];
        half8 bf[6][2];
#pragma unroll
        for (int amt = 0; amt < 2; ++amt) {
            af[amt][0] = frag_ld(xls[buf], rbase + amt * 16 + lq, 16 * g);
            af[amt][1] = frag_ld(xls[buf], rbase + amt * 16 + lq, 64 + 16 * g);
        }
#pragma unroll
        for (int ct = 0; ct < 6; ++ct) {
            int wr = cbase + ct * 16 + lq;
            bf[ct][0] = frag_ld(wls[buf], wr, 16 * g);
            bf[ct][1] = frag_ld(wls[buf], wr, 64 + 16 * g);
        }
        asm volatile("s_waitcnt lgkmcnt(0)" ::: "memory");
        __builtin_amdgcn_sched_barrier(0);
        __builtin_amdgcn_s_barrier();
        if (ks + 2 < 8) stage(buf, ks + 2);
        __builtin_amdgcn_s_setprio(1);
#pragma unroll
        for (int ct = 0; ct < 6; ++ct) {
#pragma unroll
            for (int amt = 0; amt < 2; ++amt) {
                acc[amt][ct] = __builtin_amdgcn_mfma_f32_16x16x32_f16(af[amt][0], bf[ct][0], acc[amt][ct], 0, 0, 0);
                acc[amt][ct] = __builtin_amdgcn_mfma_f32_16x16x32_f16(af[amt][1], bf[ct][1], acc[amt][ct], 0, 0, 0);
            }
        }
        __builtin_amdgcn_s_setprio(0);
    }

    // ---- coalesced epilogue via LDS transpose (reuse wls as scratch) ----
    const int b0 = m0 >> 11;
    const int nb0 = m0 & (NN - 1);
    const size_t bh = (size_t)(b0 * HH + h);
    _Float16* ldsA = &wls[0][0];
    _Float16* ldsV = &wls[0][0];
    const int rn = t >> 2;
    const int rc = t & 3;

    // Pass A: Q
    __syncthreads();
    if ((wave & 1) == 0) {
#pragma unroll
        for (int ct = 0; ct < 4; ++ct) {
            int o = ct * 16 + lq;
#pragma unroll
            for (int amt = 0; amt < 2; ++amt)
#pragma unroll
                for (int i = 0; i < 4; ++i) {
                    int n = rbase + amt * 16 + 4 * g + i;
                    ldsA[n * 72 + o] = (_Float16)(acc[amt][ct][i] * 0.18033688011112042f);
                }
        }
    }
    __syncthreads();
    {
        half8 v0 = *(const half8*)&ldsA[rn * 72 + rc * 16];
        half8 v1 = *(const half8*)&ldsA[rn * 72 + rc * 16 + 8];
        _Float16* qp = qsp + (bh * NN + nb0 + rn) * VD + rc * 16;
        *(half8*)qp = v0;
        *(half8*)(qp + 8) = v1;
    }

    // Pass B: K
    __syncthreads();
    if ((wave & 1) == 0) {
#pragma unroll
        for (int ct = 4; ct < 6; ++ct) {
            int o = (ct - 4) * 16 + lq;
#pragma unroll
            for (int amt = 0; amt < 2; ++amt)
#pragma unroll
                for (int i = 0; i < 4; ++i) {
                    int n = rbase + amt * 16 + 4 * g + i;
                    ldsA[n * 72 + o] = (_Float16)acc[amt][ct][i];
                }
        }
    } else {
#pragma unroll
        for (int ct = 0; ct < 2; ++ct) {
            int o = 32 + ct * 16 + lq;
#pragma unroll
            for (int amt = 0; amt < 2; ++amt)
#pragma unroll
                for (int i = 0; i < 4; ++i) {
                    int n = rbase + amt * 16 + 4 * g + i;
                    ldsA[n * 72 + o] = (_Float16)acc[amt][ct][i];
                }
        }
    }
    __syncthreads();
    {
        half8 v0 = *(const half8*)&ldsA[rn * 72 + rc * 16];
        half8 v1 = *(const half8*)&ldsA[rn * 72 + rc * 16 + 8];
        _Float16* kp = kbp + (bh * NN + nb0 + rn) * VD + rc * 16;
        *(half8*)kp = v0;
        *(half8*)(kp + 8) = v1;
    }

    // Pass C: V (psi folded into reads)
    __syncthreads();
    if (wave & 1) {
#pragma unroll
        for (int ct = 2; ct < 6; ++ct) {
            int o = (ct - 2) * 16 + lq;
#pragma unroll
            for (int amt = 0; amt < 2; ++amt) {
                int n0 = rbase + amt * 16 + 4 * g;
                half4 hv;
#pragma unroll
                for (int i = 0; i < 4; ++i) hv[i] = (_Float16)acc[amt][ct][i];
                *(half4*)&ldsV[o * 88 + n0] = hv;
            }
        }
    }
    __syncthreads();
    {
#pragma unroll
        for (int blk = 0; blk < 2; ++blk) {
            half4 lo = *(const half4*)&ldsV[rn * 88 + 32 * blk + 4 * rc];
            half4 hi = *(const half4*)&ldsV[rn * 88 + 32 * blk + 16 + 4 * rc];
            half8 pk;
            pk[0] = lo[0]; pk[1] = lo[1]; pk[2] = lo[2]; pk[3] = lo[3];
            pk[4] = hi[0]; pk[5] = hi[1]; pk[6] = hi[2]; pk[7] = hi[3];
            *(half8*)(vtp + (bh * VD + rn) * NN + nb0 + 32 * blk + 8 * rc) = pk;
        }
    }
}

// ---------------------------------------------------------------------------
// Kernel 3: flash attention v11 -- BARRIER-FREE k-loop. K staging/reads were
// already wave-private (v9); V is re-laid out wave-private too: each wave
// stages [64 d][32 kv] of its own kv chunk into its own 4KB region, with
// chunk swizzle s = c ^ (r&3) ^ ((r>>2)&3) (2-way bank alias on reads).
// Zero cross-wave LDS deps -> both per-tile barriers deleted; each wave
// free-runs on its counted vmcnt(8) double buffer. Epilogue sred rows
// padded to 68 floats (16-way -> 2-way conflicts).
// ---------------------------------------------------------------------------
__global__ __launch_bounds__(256, 2) void k_attn(
    const _Float16* __restrict__ qs,
    const _Float16* __restrict__ kb,
    const _Float16* __restrict__ vt,
    float* __restrict__ out)
{
    constexpr int NITER = NN / 128;    // 16
    __shared__ __align__(16) char SM[SM_BYTES];
    const int bid = blockIdx.x, t = threadIdx.x;
    const int wave = t >> 6, lane = t & 63;
    const int lq = lane & 15, g = lane >> 4;
    const int xcd = bid & 7;
    const int bh = xcd * 2 + ((bid >> 3) & 1);
    const int qt = bid >> 4;
    const int qbase = qt * 64;

    half8 qf[4][2];
#pragma unroll
    for (int qg = 0; qg < 4; ++qg)
#pragma unroll
        for (int ds = 0; ds < 2; ++ds)
            qf[qg][ds] = *(const half8*)(qs + ((size_t)bh * NN + qbase + 16 * qg + lq) * VD + 32 * ds + 8 * g);

    const int r8 = lane >> 3;
    // K staging source (wave-private rows 32w..32w+31), d-chunk XOR swizzle
    const _Float16* kS = kb + ((size_t)bh * NN + 32 * wave + r8) * VD + 8 * ((lane & 7) ^ r8);
    // V staging sources: load uu covers d rows 16uu..16uu+15, 32 kv of this
    // wave's chunk; lane (r = lane>>2, s = lane&3) fetches storage chunk
    // c = s ^ (r&3) ^ ((r>>2)&3) of row 16uu+r.
    const int vr = lane >> 2, vs = lane & 3;
    const int vc = vs ^ (vr & 3) ^ ((vr >> 2) & 3);
    const _Float16* vS[4];
#pragma unroll
    for (int uu = 0; uu < 4; ++uu)
        vS[uu] = vt + ((size_t)bh * VD + 16 * uu + vr) * NN + 32 * wave + 8 * vc;

    _Float16* kb0 = (_Float16*)(SM);
    _Float16* vb0 = (_Float16*)(SM + 16384);
    _Float16* kb1 = (_Float16*)(SM + 32768);
    _Float16* vb1 = (_Float16*)(SM + 49152);

    auto stage = [&](int b, int j) {
        _Float16* kd = (b ? kb1 : kb0) + 4 * wave * 512;
        const _Float16* kp = kS + (size_t)j * 128 * VD;
#pragma unroll
        for (int uu = 0; uu < 4; ++uu)
            GLDS16(kp + uu * 8 * VD, kd + uu * 512);
        _Float16* vd = (b ? vb1 : vb0) + 4 * wave * 512;
#pragma unroll
        for (int uu = 0; uu < 4; ++uu)
            GLDS16(vS[uu] + j * 128, vd + uu * 512);
    };

    f32x4 oacc[4][4];
    f32x4 oacc_l[4];
#pragma unroll
    for (int qg = 0; qg < 4; ++qg) {
#pragma unroll
        for (int dt = 0; dt < 4; ++dt) oacc[qg][dt] = (f32x4){0.f, 0.f, 0.f, 0.f};
        oacc_l[qg] = (f32x4){0.f, 0.f, 0.f, 0.f};
    }
    half8 vones;
#pragma unroll
    for (int i = 0; i < 8; ++i) vones[i] = (_Float16)1.0f;

    stage(0, 0);
    stage(1, 1);

    union PU { fp16x2 h2[4]; half8 h8; };
    const int vread = lq * 32 + 8 * (g ^ (lq & 3) ^ ((lq >> 2) & 3));

    for (int j = 0; j < NITER; ++j) {
        const int b = j & 1;
        if (j < NITER - 1) asm volatile("s_waitcnt vmcnt(8)" ::: "memory");
        else               asm volatile("s_waitcnt vmcnt(0)" ::: "memory");
        const _Float16* kB = (b ? kb1 : kb0) + 4 * wave * 512 - (size_t)(32 * wave) * 64;
        const _Float16* vW = (b ? vb1 : vb0) + 4 * wave * 512;
        half8 kf[2][2], vf[4];
#pragma unroll
        for (int mt = 0; mt < 2; ++mt)
#pragma unroll
            for (int ds = 0; ds < 2; ++ds)
                kf[mt][ds] = frag_ld(kB, 32 * wave + 16 * mt + lq, 64 * ds + 16 * g);
#pragma unroll
        for (int dt = 0; dt < 4; ++dt)
            vf[dt] = *(const half8*)(vW + dt * 512 + vread);
        asm volatile("s_waitcnt lgkmcnt(0)" ::: "memory");
        __builtin_amdgcn_sched_barrier(0);
        if (j + 2 < NITER) stage(b, j + 2);
        f32x4 sc[2][2];
        __builtin_amdgcn_s_setprio(1);
#pragma unroll
        for (int mt = 0; mt < 2; ++mt) {
            sc[0][mt] = (f32x4){0.f, 0.f, 0.f, 0.f};
            sc[0][mt] = __builtin_amdgcn_mfma_f32_16x16x32_f16(kf[mt][0], qf[0][0], sc[0][mt], 0, 0, 0);
            sc[0][mt] = __builtin_amdgcn_mfma_f32_16x16x32_f16(kf[mt][1], qf[0][1], sc[0][mt], 0, 0, 0);
        }
#pragma unroll
        for (int qg = 0; qg < 4; ++qg) {
            const int cur = qg & 1;
            if (qg < 3) {
#pragma unroll
                for (int mt = 0; mt < 2; ++mt) {
                    sc[cur ^ 1][mt] = (f32x4){0.f, 0.f, 0.f, 0.f};
                    sc[cur ^ 1][mt] = __builtin_amdgcn_mfma_f32_16x16x32_f16(kf[mt][0], qf[qg + 1][0], sc[cur ^ 1][mt], 0, 0, 0);
                    sc[cur ^ 1][mt] = __builtin_amdgcn_mfma_f32_16x16x32_f16(kf[mt][1], qf[qg + 1][1], sc[cur ^ 1][mt], 0, 0, 0);
                }
            }
            PU pu;
            {
                float p00 = fexp2(sc[cur][0][0]);
                float p01 = fexp2(sc[cur][0][1]);
                float p02 = fexp2(sc[cur][0][2]);
                float p03 = fexp2(sc[cur][0][3]);
                float p10 = fexp2(sc[cur][1][0]);
                float p11 = fexp2(sc[cur][1][1]);
                float p12 = fexp2(sc[cur][1][2]);
                float p13 = fexp2(sc[cur][1][3]);
                pu.h2[0] = __builtin_amdgcn_cvt_pkrtz(p00, p01);
                pu.h2[1] = __builtin_amdgcn_cvt_pkrtz(p02, p03);
                pu.h2[2] = __builtin_amdgcn_cvt_pkrtz(p10, p11);
                pu.h2[3] = __builtin_amdgcn_cvt_pkrtz(p12, p13);
            }
#pragma unroll
            for (int dt = 0; dt < 4; ++dt)
                oacc[qg][dt] = __builtin_amdgcn_mfma_f32_16x16x32_f16(vf[dt], pu.h8, oacc[qg][dt], 0, 0, 0);
            oacc_l[qg] = __builtin_amdgcn_mfma_f32_16x16x32_f16(vones, pu.h8, oacc_l[qg], 0, 0, 0);
        }
        __builtin_amdgcn_s_setprio(0);
    }

    // ---- epilogue: cross-wave reduce, 68-float padded rows (2-way banks) ----
    float* sred = (float*)SM;             // [4 waves][64 q][68 pad]
    float* lsm  = (float*)(SM + 69632);   // [4 waves][64 q]
    __syncthreads();
    if (g == 0) {
#pragma unroll
        for (int qg = 0; qg < 4; ++qg) lsm[wave * 64 + 16 * qg + lq] = oacc_l[qg][0];
    }
#pragma unroll
    for (int qg = 0; qg < 4; ++qg)
#pragma unroll
        for (int dt = 0; dt < 4; ++dt)
            *(f32x4*)(sred + (size_t)wave * 4352 + (16 * qg + lq) * 68 + 16 * dt + 4 * g) = oacc[qg][dt];
    __syncthreads();
    const int b2 = bh >> 3, h = bh & 7;
    const int q = t >> 2, cg2 = t & 3;
    float lt = (lsm[q] + lsm[64 + q]) + (lsm[128 + q] + lsm[192 + q]);
    float inv = 1.f / lt;
    float* op = out + ((size_t)b2 * NN + qbase + q) * (HH * VD) + h * VD + 16 * cg2;
#pragma unroll
    for (int c2 = 0; c2 < 4; ++c2) {
        int off = q * 68 + 16 * cg2 + 4 * c2;
        f32x4 o = *(const f32x4*)(sred + off);
        o += *(const f32x4*)(sred + 4352 + off);
        o += *(const f32x4*)(sred + 8704 + off);
        o += *(const f32x4*)(sred + 13056 + off);
        float4 r;
        r.x = gelu_exact(o[0] * inv);
        r.y = gelu_exact(o[1] * inv);
        r.z = gelu_exact(o[2] * inv);
        r.w = gelu_exact(o[3] * inv);
        *(float4*)(op + 4 * c2) = r;
    }
}

// ---------------------------------------------------------------------------
extern "C" void kernel_launch(void* const* d_in, const int* in_sizes, int n_in,
                              void* d_out, int out_size, void* d_ws, size_t ws_size,
                              hipStream_t stream)
{
    const float* x  = (const float*)d_in[0];
    const float* qw = (const float*)d_in[1];
    const float* kw = (const float*)d_in[2];
    const float* vw = (const float*)d_in[3];
    float* out = (float*)d_out;

    _Float16* wt  = (_Float16*)d_ws;            // [3][H][VD][D]
    _Float16* xhp = wt  + 786432;               // [B*N][D]
    _Float16* qsp = xhp + 2097152;
    _Float16* kbp = qsp + 2097152;
    _Float16* vtp = kbp + 2097152;

    hipLaunchKernelGGL(k_prep, dim3(512), dim3(256), 0, stream,
                       x, qw, kw, vw, wt, xhp);
    hipLaunchKernelGGL(k_proj, dim3(512), dim3(256), 0, stream,
                       xhp, wt, qsp, kbp, vtp);
    hipLaunchKernelGGL(k_attn, dim3(512), dim3(256), 0, stream,
                       qsp, kbp, vtp, out);
}